// Round 7
// baseline (674.327 us; speedup 1.0000x reference)
//
#include <hip/hip_runtime.h>
#include <cstdint>
#include <cstddef>

#define RANGE    128       // nodes per fine bucket
#define RSHIFT   7
#define MAXBUCK  800       // >= ceil(N/RANGE); N=100K -> 782
#define CSHIFT   12        // nodes per coarse bucket = 4096
#define CRANGE   4096
#define MAXC     32        // >= ceil(N/CRANGE); N=100K -> 25
#define FPB      32        // fine buckets per coarse bucket
#define CH_CNT   8192      // edges per block, count pass (782 blocks)
#define CH_SC    4096      // edges per block, scatter passes
#define PAD      16        // pad global counters to one 64B line each

typedef _Float16 h8 __attribute__((ext_vector_type(8)));
typedef _Float16 h4 __attribute__((ext_vector_type(4)));

// ---------------------------------------------------------------------------
__global__ void zero_pad_kernel(int* __restrict__ p, int n) {
    int i = blockIdx.x * blockDim.x + threadIdx.x;
    if (i < n) p[i * PAD] = 0;
}

// fine histogram (782 buckets) of col>>7; per-block LDS, merged w/ global atomics
__global__ void count_kernel(const int* __restrict__ col, int* __restrict__ fcnt,
                             int nfine, int E) {
    __shared__ int lcnt[MAXBUCK];
    int tid = threadIdx.x;
    for (int i = tid; i < nfine; i += blockDim.x) lcnt[i] = 0;
    __syncthreads();
    int base = blockIdx.x * CH_CNT;
    int end  = min(E, base + CH_CNT);
    for (int e = base + tid; e < end; e += blockDim.x)
        atomicAdd(&lcnt[col[e] >> RSHIFT], 1);
    __syncthreads();
    for (int i = tid; i < nfine; i += blockDim.x)
        if (lcnt[i]) atomicAdd(&fcnt[i * PAD], lcnt[i]);
}

// scan fine counts -> fine bases/cursors; derive coarse bases/cursors
__global__ void scan_kernel(const int* __restrict__ fcnt, int* __restrict__ fbase,
                            int* __restrict__ fcur, int* __restrict__ cbase,
                            int* __restrict__ ccur, int* __restrict__ row_ptr,
                            int nfine, int ncoarse, int N, int E) {
    __shared__ int lds[1024];
    int T = threadIdx.x;
    int s = (T < nfine) ? fcnt[T * PAD] : 0;
    lds[T] = s;
    __syncthreads();
    for (int off = 1; off < 1024; off <<= 1) {
        int v = (T >= off) ? lds[T - off] : 0;
        __syncthreads();
        lds[T] += v;
        __syncthreads();
    }
    int excl = lds[T] - s;
    if (T < nfine) { fbase[T] = excl; fcur[T * PAD] = excl; }
    if ((T & (FPB - 1)) == 0 && (T >> 5) < ncoarse) {
        cbase[T >> 5] = excl;
        ccur[(T >> 5) * PAD] = excl;
    }
    if (T == 0) { fbase[nfine] = E; cbase[ncoarse] = E; row_ptr[N] = E; }
}

// coarse scatter: 25 buckets (col>>12) -> partA.  record = {row | col_low12<<17, ew}
__global__ void coarse_scatter_kernel(const int* __restrict__ row, const int* __restrict__ col,
                                      const float* __restrict__ ew, int* __restrict__ ccur,
                                      uint2* __restrict__ partA, int ncoarse, int E) {
    __shared__ int lcnt[MAXC];
    __shared__ int lbase[MAXC];
    int tid = threadIdx.x;
    if (tid < MAXC) lcnt[tid] = 0;
    __syncthreads();
    int base = blockIdx.x * CH_SC;
    int end  = min(E, base + CH_SC);
    for (int e = base + tid; e < end; e += blockDim.x)
        atomicAdd(&lcnt[col[e] >> CSHIFT], 1);
    __syncthreads();
    if (tid < ncoarse) {
        int c = lcnt[tid];
        lbase[tid] = c ? atomicAdd(&ccur[tid * PAD], c) : 0;
        lcnt[tid] = 0;
    }
    __syncthreads();
    for (int e = base + tid; e < end; e += blockDim.x) {
        int c = col[e];
        int b = c >> CSHIFT;
        int off = atomicAdd(&lcnt[b], 1);
        partA[lbase[b] + off] =
            make_uint2((unsigned)row[e] | ((unsigned)(c & (CRANGE - 1)) << 17),
                       __float_as_uint(ew[e]));
    }
}

// fine scatter: partA (coarsely sorted) -> partB grouped by 128-node fine bucket.
// output record = {row | dst_local<<17, ew}
__global__ void fine_scatter_kernel(const uint2* __restrict__ partA, const int* __restrict__ cbase,
                                    int* __restrict__ fcur, uint2* __restrict__ partB,
                                    int nfine, int ncoarse, int E) {
    __shared__ int lcnt[MAXBUCK];
    __shared__ int lbase[MAXBUCK];
    __shared__ int scb[MAXC + 1];
    __shared__ int rlo_s;
    int tid = threadIdx.x;
    int base = blockIdx.x * CH_SC;
    int end  = min(E, base + CH_SC);
    if (tid <= ncoarse) scb[tid] = cbase[tid];
    for (int i = tid; i < nfine; i += blockDim.x) lcnt[i] = 0;
    if (tid == 0) {
        int r = 0;
        while (r < ncoarse - 1 && cbase[r + 1] <= base) ++r;
        rlo_s = r;
    }
    __syncthreads();
    int rlo = rlo_s;
    for (int e = base + tid; e < end; e += blockDim.x) {
        int r = rlo;
        while (e >= scb[r + 1]) ++r;
        int col12 = (int)((partA[e].x >> 17) & (CRANGE - 1));
        atomicAdd(&lcnt[(r << 5) | (col12 >> RSHIFT)], 1);
    }
    __syncthreads();
    for (int i = tid; i < nfine; i += blockDim.x) {
        int c = lcnt[i];
        lbase[i] = c ? atomicAdd(&fcur[i * PAD], c) : 0;
        lcnt[i] = 0;
    }
    __syncthreads();
    for (int e = base + tid; e < end; e += blockDim.x) {
        uint2 v = partA[e];
        int r = rlo;
        while (e >= scb[r + 1]) ++r;
        int col12 = (int)((v.x >> 17) & (CRANGE - 1));
        int f = (r << 5) | (col12 >> RSHIFT);
        int off = atomicAdd(&lcnt[f], 1);
        partB[lbase[f] + off] =
            make_uint2((v.x & 0x1FFFFu) | ((unsigned)(col12 & (RANGE - 1)) << 17), v.y);
    }
}

// one block per fine bucket: dis[node] = rsqrt(1 + sum ew into node)
__global__ void deg_dis_kernel(const uint2* __restrict__ part, const int* __restrict__ bbase,
                               float* __restrict__ dis, int N) {
    __shared__ float sdeg[RANGE];
    int b = blockIdx.x, tid = threadIdx.x;
    int s = bbase[b], t = bbase[b + 1];
    if (tid < RANGE) sdeg[tid] = 1.0f;  // self-loop weight
    __syncthreads();
    for (int e = s + tid; e < t; e += blockDim.x) {
        uint2 r = part[e];
        atomicAdd(&sdeg[(r.x >> 17) & (RANGE - 1)], __uint_as_float(r.y));
    }
    __syncthreads();
    int node = b * RANGE + tid;
    if (tid < RANGE && node < N) dis[node] = rsqrtf(sdeg[tid]);
}

// one block per fine bucket: per-node CSR with PRE-NORMALIZED edge weights.
// csr[pos] = {src, norm = dis[dst]*ew*dis[src]}  — aggs become pure readers.
__global__ void bucket_csr_kernel(const uint2* __restrict__ part, const int* __restrict__ bbase,
                                  const float* __restrict__ dis, int* __restrict__ row_ptr,
                                  uint2* __restrict__ csr, int N) {
    __shared__ int   scnt[RANGE];
    __shared__ int   sscan[RANGE];
    __shared__ float sdis[RANGE];
    int b = blockIdx.x, tid = threadIdx.x;
    int s = bbase[b], t = bbase[b + 1];
    if (tid < RANGE) {
        scnt[tid] = 0;
        int node = b * RANGE + tid;
        sdis[tid] = (node < N) ? dis[node] : 0.f;
    }
    __syncthreads();
    for (int e = s + tid; e < t; e += blockDim.x)
        atomicAdd(&scnt[(part[e].x >> 17) & (RANGE - 1)], 1);
    __syncthreads();
    int cnt_t = 0;
    if (tid < RANGE) { cnt_t = scnt[tid]; sscan[tid] = cnt_t; }
    __syncthreads();
    for (int off = 1; off < RANGE; off <<= 1) {
        int v = 0;
        if (tid < RANGE && tid >= off) v = sscan[tid - off];
        __syncthreads();
        if (tid < RANGE) sscan[tid] += v;
        __syncthreads();
    }
    if (tid < RANGE) {
        int excl = sscan[tid] - cnt_t;
        int node = b * RANGE + tid;
        if (node < N) row_ptr[node] = s + excl;
        scnt[tid] = excl;  // reuse as within-bucket cursor
    }
    __syncthreads();
    for (int e = s + tid; e < t; e += blockDim.x) {
        uint2 r = part[e];
        int c   = (r.x >> 17) & (RANGE - 1);
        int src = (int)(r.x & 0x1FFFFu);
        float norm = sdis[c] * __uint_as_float(r.y) * dis[src];
        int off = atomicAdd(&scnt[c], 1);
        csr[s + off] = make_uint2((unsigned)src, __float_as_uint(norm));
    }
}

// t1 = fp16(X @ W1)   ([N,128] @ [128,12], row = 16 halves = 32 B); wave/node
__global__ void lin1_kernel(const float* __restrict__ X, const float* __restrict__ W1,
                            _Float16* __restrict__ t1, int n) {
    int node = (int)((blockIdx.x * (size_t)blockDim.x + threadIdx.x) >> 6);
    int lane = threadIdx.x & 63;
    if (node >= n) return;
    const float* xr = X + (size_t)node * 128;
    float x0 = xr[lane];
    float x1 = xr[lane + 64];
    float res[12];
#pragma unroll
    for (int o = 0; o < 12; o++) {
        float p = x0 * W1[lane * 12 + o] + x1 * W1[(lane + 64) * 12 + o];
#pragma unroll
        for (int off = 32; off > 0; off >>= 1) p += __shfl_xor(p, off, 64);
        res[o] = p;
    }
    if (lane == 0) {
        h8 a, b;
#pragma unroll
        for (int o = 0; o < 8; o++) a[o] = (_Float16)res[o];
#pragma unroll
        for (int o = 0; o < 4; o++) b[o] = (_Float16)res[8 + o];
#pragma unroll
        for (int o = 4; o < 8; o++) b[o] = (_Float16)0.f;
        h8* dst = (h8*)(t1 + (size_t)node * 16);
        dst[0] = a;
        dst[1] = b;
    }
}

// Pull aggregation, 8 lanes per node. csr is read-only {src, norm};
// features fp16 rows (SINH halves). Nontemporal csr stream keeps feature
// table L2-resident. Epilogue fuses bias+relu+next matvec (or sigmoid).
template <int DIN, int SINH, int DOUT, int SOUTH, bool LAST>
__global__ void agg_kernel(const int* __restrict__ row_ptr, const uint2* __restrict__ csr,
                           const float* __restrict__ dis, const _Float16* __restrict__ hin,
                           const float* __restrict__ b_this, const float* __restrict__ W_next,
                           const float* __restrict__ b_next, void* __restrict__ hout_v, int n) {
    int gt   = blockIdx.x * blockDim.x + threadIdx.x;
    int node = gt >> 3;
    int sub  = gt & 7;
    if (node >= n) return;
    int start = row_ptr[node];
    int end   = row_ptr[node + 1];
    float acc[DIN];
#pragma unroll
    for (int d = 0; d < DIN; d++) acc[d] = 0.f;

    for (int e = start + sub; e < end; e += 8) {
        unsigned long long raw =
            __builtin_nontemporal_load((const unsigned long long*)(csr + e));
        int src    = (int)(unsigned)raw;
        float norm = __uint_as_float((unsigned)(raw >> 32));
        const _Float16* hr = hin + (size_t)src * SINH;
        if constexpr (DIN == 12) {
            h8 a = ((const h8*)hr)[0];
            h8 b = ((const h8*)hr)[1];
#pragma unroll
            for (int d = 0; d < 8; d++) acc[d] += norm * (float)a[d];
#pragma unroll
            for (int d = 0; d < 4; d++) acc[8 + d] += norm * (float)b[d];
        } else if constexpr (DIN == 6) {
            h8 a = *(const h8*)hr;
#pragma unroll
            for (int d = 0; d < 6; d++) acc[d] += norm * (float)a[d];
        } else {  // DIN == 3
            h4 a = *(const h4*)hr;
#pragma unroll
            for (int d = 0; d < 3; d++) acc[d] += norm * (float)a[d];
        }
    }

#pragma unroll
    for (int d = 0; d < DIN; d++) {
        acc[d] += __shfl_xor(acc[d], 1, 64);
        acc[d] += __shfl_xor(acc[d], 2, 64);
        acc[d] += __shfl_xor(acc[d], 4, 64);
    }

    if (sub == 0) {
        float dn = dis[node];
        float s2 = dn * dn;
        const _Float16* hn = hin + (size_t)node * SINH;
        float v[DIN];
#pragma unroll
        for (int d = 0; d < DIN; d++)
            v[d] = fmaxf(acc[d] + s2 * (float)hn[d] + b_this[d], 0.f);
        if constexpr (!LAST) {
            float o[DOUT];
#pragma unroll
            for (int oo = 0; oo < DOUT; oo++) {
                float z = 0.f;
#pragma unroll
                for (int d = 0; d < DIN; d++) z += v[d] * W_next[d * DOUT + oo];
                o[oo] = z;
            }
            _Float16* op = (_Float16*)hout_v + (size_t)node * SOUTH;
            if constexpr (DOUT == 6) {
                h8 w;
#pragma unroll
                for (int oo = 0; oo < 6; oo++) w[oo] = (_Float16)o[oo];
                w[6] = (_Float16)0.f; w[7] = (_Float16)0.f;
                *(h8*)op = w;
            } else {  // DOUT == 3, SOUTH == 4
                h4 w;
#pragma unroll
                for (int oo = 0; oo < 3; oo++) w[oo] = (_Float16)o[oo];
                w[3] = (_Float16)0.f;
                *(h4*)op = w;
            }
        } else {
            float z = b_next[0];
#pragma unroll
            for (int d = 0; d < DIN; d++) z += v[d] * W_next[d];
            ((float*)hout_v)[node] = 1.0f / (1.0f + expf(-z));
        }
    }
}

// ---------------------------------------------------------------------------
extern "C" void kernel_launch(void* const* d_in, const int* in_sizes, int n_in,
                              void* d_out, int out_size, void* d_ws, size_t ws_size,
                              hipStream_t stream) {
    const float* X  = (const float*)d_in[0];
    const int*   ei = (const int*)d_in[1];
    const float* ew = (const float*)d_in[2];
    const float* W1 = (const float*)d_in[3];
    const float* b1 = (const float*)d_in[4];
    const float* W2 = (const float*)d_in[5];
    const float* b2 = (const float*)d_in[6];
    const float* W3 = (const float*)d_in[7];
    const float* b3 = (const float*)d_in[8];
    const float* Wl = (const float*)d_in[9];
    const float* bl = (const float*)d_in[10];
    float* out = (float*)d_out;

    const int N = in_sizes[0] / 128;
    const int E = in_sizes[1] / 2;
    const int* row = ei;
    const int* col = ei + E;
    const int nfine   = (N + RANGE - 1) >> RSHIFT;
    const int ncoarse = (N + CRANGE - 1) >> CSHIFT;

    char* ws = (char*)d_ws;
    size_t off = 0;
    auto carve = [&](size_t bytes) -> void* {
        void* p = ws + off;
        off += (bytes + 255) & ~(size_t)255;
        return p;
    };
    int*   fcnt    = (int*)  carve((size_t)MAXBUCK * PAD * 4);
    int*   fcur    = (int*)  carve((size_t)MAXBUCK * PAD * 4);
    int*   ccur    = (int*)  carve((size_t)MAXC * PAD * 4);
    int*   cbase   = (int*)  carve((size_t)(MAXC + 1) * 4);
    int*   fbase   = (int*)  carve((size_t)(MAXBUCK + 1) * 4);
    int*   row_ptr = (int*)  carve((size_t)(N + 1) * 4);
    float* dis     = (float*)carve((size_t)N * 4);
    uint2* partA   = (uint2*)carve((size_t)E * 8);
    uint2* partB   = (uint2*)carve((size_t)E * 8);
    // csr reuses partA (dead after fine scatter); t1/t2/t3 reuse partB
    // (dead after bucket_csr; lin1 launches after bucket_csr)
    uint2*    csr = partA;
    _Float16* t1  = (_Float16*)partB;
    _Float16* t2  = t1 + (size_t)N * 16;
    _Float16* t3  = t2 + (size_t)N * 8;
    (void)ws_size; (void)n_in; (void)out_size;

    const int bCnt = (E + CH_CNT - 1) / CH_CNT;    // 782 count blocks
    const int bSc  = (E + CH_SC - 1) / CH_SC;      // 1563 scatter blocks
    const int bW   = (N + 3) / 4;                  // lin1: wave per node
    const int bA   = ((size_t)N * 8 + 255) / 256;  // agg: 8 lanes per node

    zero_pad_kernel<<<(nfine + 255) / 256, 256, 0, stream>>>(fcnt, nfine);
    count_kernel<<<bCnt, 256, 0, stream>>>(col, fcnt, nfine, E);
    scan_kernel<<<1, 1024, 0, stream>>>(fcnt, fbase, fcur, cbase, ccur, row_ptr,
                                        nfine, ncoarse, N, E);
    coarse_scatter_kernel<<<bSc, 256, 0, stream>>>(row, col, ew, ccur, partA, ncoarse, E);
    fine_scatter_kernel<<<bSc, 256, 0, stream>>>(partA, cbase, fcur, partB, nfine, ncoarse, E);
    deg_dis_kernel<<<nfine, 256, 0, stream>>>(partB, fbase, dis, N);
    bucket_csr_kernel<<<nfine, 256, 0, stream>>>(partB, fbase, dis, row_ptr, csr, N);
    lin1_kernel<<<bW, 256, 0, stream>>>(X, W1, t1, N);
    agg_kernel<12, 16, 6, 8, false><<<bA, 256, 0, stream>>>(row_ptr, csr, dis, t1, b1, W2, nullptr, t2, N);
    agg_kernel< 6,  8, 3, 4, false><<<bA, 256, 0, stream>>>(row_ptr, csr, dis, t2, b2, W3, nullptr, t3, N);
    agg_kernel< 3,  4, 1, 1, true ><<<bA, 256, 0, stream>>>(row_ptr, csr, dis, t3, b3, Wl, bl, out, N);
}

// Round 8
// 645.917 us; speedup vs baseline: 1.0440x; 1.0440x over previous
//
#include <hip/hip_runtime.h>
#include <cstdint>
#include <cstddef>

#define RANGE    128       // nodes per fine bucket
#define RSHIFT   7
#define MAXBUCK  800       // >= ceil(N/RANGE); N=100K -> 782
#define CSHIFT   12        // nodes per coarse bucket = 4096
#define CRANGE   4096
#define MAXC     32        // >= ceil(N/CRANGE); N=100K -> 25
#define FPB      32        // fine buckets per coarse bucket
#define CH_CNT   8192      // edges per block, count pass
#define CH_C     2048      // edges per block, coarse scatter (3126 blocks)
#define CH_F     4096      // edges per block, fine scatter
#define PAD      16        // pad global counters to one 64B line each

typedef _Float16 h8 __attribute__((ext_vector_type(8)));

// ---------------------------------------------------------------------------
__global__ void zero_pad_kernel(int* __restrict__ p, int n) {
    int i = blockIdx.x * blockDim.x + threadIdx.x;
    if (i < n) p[i * PAD] = 0;
}

// fine histogram (782 buckets) of col>>7; per-block LDS, merged w/ global atomics
__global__ void count_kernel(const int* __restrict__ col, int* __restrict__ fcnt,
                             int nfine, int E) {
    __shared__ int lcnt[MAXBUCK];
    int tid = threadIdx.x;
    for (int i = tid; i < nfine; i += blockDim.x) lcnt[i] = 0;
    __syncthreads();
    int base = blockIdx.x * CH_CNT;
    int end  = min(E, base + CH_CNT);
    for (int e = base + tid; e < end; e += blockDim.x)
        atomicAdd(&lcnt[col[e] >> RSHIFT], 1);
    __syncthreads();
    for (int i = tid; i < nfine; i += blockDim.x)
        if (lcnt[i]) atomicAdd(&fcnt[i * PAD], lcnt[i]);
}

// scan fine counts -> fine bases/cursors; derive coarse bases/cursors
__global__ void scan_kernel(const int* __restrict__ fcnt, int* __restrict__ fbase,
                            int* __restrict__ fcur, int* __restrict__ cbase,
                            int* __restrict__ ccur, int* __restrict__ row_ptr,
                            int nfine, int ncoarse, int N, int E) {
    __shared__ int lds[1024];
    int T = threadIdx.x;
    int s = (T < nfine) ? fcnt[T * PAD] : 0;
    lds[T] = s;
    __syncthreads();
    for (int off = 1; off < 1024; off <<= 1) {
        int v = (T >= off) ? lds[T - off] : 0;
        __syncthreads();
        lds[T] += v;
        __syncthreads();
    }
    int excl = lds[T] - s;
    if (T < nfine) { fbase[T] = excl; fcur[T * PAD] = excl; }
    if ((T & (FPB - 1)) == 0 && (T >> 5) < ncoarse) {
        cbase[T >> 5] = excl;
        ccur[(T >> 5) * PAD] = excl;
    }
    if (T == 0) { fbase[nfine] = E; cbase[ncoarse] = E; row_ptr[N] = E; }
}

// coarse scatter: 25 buckets (col>>12) -> partA.  record = {row | col_low12<<17, ew}
__global__ void coarse_scatter_kernel(const int* __restrict__ row, const int* __restrict__ col,
                                      const float* __restrict__ ew, int* __restrict__ ccur,
                                      uint2* __restrict__ partA, int ncoarse, int E) {
    __shared__ int lcnt[MAXC];
    __shared__ int lbase[MAXC];
    int tid = threadIdx.x;
    if (tid < MAXC) lcnt[tid] = 0;
    __syncthreads();
    int base = blockIdx.x * CH_C;
    int end  = min(E, base + CH_C);
    for (int e = base + tid; e < end; e += blockDim.x)
        atomicAdd(&lcnt[col[e] >> CSHIFT], 1);
    __syncthreads();
    if (tid < ncoarse) {
        int c = lcnt[tid];
        lbase[tid] = c ? atomicAdd(&ccur[tid * PAD], c) : 0;
        lcnt[tid] = 0;
    }
    __syncthreads();
    for (int e = base + tid; e < end; e += blockDim.x) {
        int c = col[e];
        int b = c >> CSHIFT;
        int off = atomicAdd(&lcnt[b], 1);
        partA[lbase[b] + off] =
            make_uint2((unsigned)row[e] | ((unsigned)(c & (CRANGE - 1)) << 17),
                       __float_as_uint(ew[e]));
    }
}

// fine scatter: partA (coarsely sorted) -> partB grouped by 128-node fine bucket.
// output record = {row | dst_local<<17, ew}
__global__ void fine_scatter_kernel(const uint2* __restrict__ partA, const int* __restrict__ cbase,
                                    int* __restrict__ fcur, uint2* __restrict__ partB,
                                    int nfine, int ncoarse, int E) {
    __shared__ int lcnt[MAXBUCK];
    __shared__ int lbase[MAXBUCK];
    __shared__ int scb[MAXC + 1];
    __shared__ int rlo_s;
    int tid = threadIdx.x;
    int base = blockIdx.x * CH_F;
    int end  = min(E, base + CH_F);
    if (tid <= ncoarse) scb[tid] = cbase[tid];
    for (int i = tid; i < nfine; i += blockDim.x) lcnt[i] = 0;
    if (tid == 0) {
        int r = 0;
        while (r < ncoarse - 1 && cbase[r + 1] <= base) ++r;
        rlo_s = r;
    }
    __syncthreads();
    int rlo = rlo_s;
    for (int e = base + tid; e < end; e += blockDim.x) {
        int r = rlo;
        while (e >= scb[r + 1]) ++r;
        int col12 = (int)((partA[e].x >> 17) & (CRANGE - 1));
        atomicAdd(&lcnt[(r << 5) | (col12 >> RSHIFT)], 1);
    }
    __syncthreads();
    for (int i = tid; i < nfine; i += blockDim.x) {
        int c = lcnt[i];
        lbase[i] = c ? atomicAdd(&fcur[i * PAD], c) : 0;
        lcnt[i] = 0;
    }
    __syncthreads();
    for (int e = base + tid; e < end; e += blockDim.x) {
        uint2 v = partA[e];
        int r = rlo;
        while (e >= scb[r + 1]) ++r;
        int col12 = (int)((v.x >> 17) & (CRANGE - 1));
        int f = (r << 5) | (col12 >> RSHIFT);
        int off = atomicAdd(&lcnt[f], 1);
        partB[lbase[f] + off] =
            make_uint2((v.x & 0x1FFFFu) | ((unsigned)(col12 & (RANGE - 1)) << 17), v.y);
    }
}

// one block per fine bucket: per-node CSR + row_ptr + dis, all in LDS.
// deg accumulated here (LDS float atomics); csr.y = ew * dis_dst (dst-side
// prenorm using ONLY local dis) -> csr is read-only for all 3 agg layers;
// src-side dis factor travels packed inside the feature rows.
__global__ void bucket_csr_kernel(const uint2* __restrict__ part, const int* __restrict__ bbase,
                                  int* __restrict__ row_ptr, float* __restrict__ dis,
                                  uint2* __restrict__ csr, int N) {
    __shared__ int   scnt[RANGE];
    __shared__ int   sscan[RANGE];
    __shared__ float sdeg[RANGE];
    __shared__ float sdis[RANGE];
    int b = blockIdx.x, tid = threadIdx.x;
    int s = bbase[b], t = bbase[b + 1];
    if (tid < RANGE) { scnt[tid] = 0; sdeg[tid] = 1.0f; }  // self-loop weight
    __syncthreads();
    for (int e = s + tid; e < t; e += blockDim.x) {
        uint2 r = part[e];
        int c = (r.x >> 17) & (RANGE - 1);
        atomicAdd(&scnt[c], 1);
        atomicAdd(&sdeg[c], __uint_as_float(r.y));
    }
    __syncthreads();
    int cnt_t = 0;
    if (tid < RANGE) { cnt_t = scnt[tid]; sscan[tid] = cnt_t; }
    __syncthreads();
    for (int off = 1; off < RANGE; off <<= 1) {
        int v = 0;
        if (tid < RANGE && tid >= off) v = sscan[tid - off];
        __syncthreads();
        if (tid < RANGE) sscan[tid] += v;
        __syncthreads();
    }
    if (tid < RANGE) {
        int excl = sscan[tid] - cnt_t;
        int node = b * RANGE + tid;
        float dn = rsqrtf(sdeg[tid]);
        sdis[tid] = dn;
        if (node < N) {
            row_ptr[node] = s + excl;
            dis[node] = dn;
        }
        scnt[tid] = excl;  // reuse as within-bucket cursor
    }
    __syncthreads();
    for (int e = s + tid; e < t; e += blockDim.x) {
        uint2 r = part[e];
        int c   = (r.x >> 17) & (RANGE - 1);
        int src = (int)(r.x & 0x1FFFFu);
        float v = sdis[c] * __uint_as_float(r.y);   // ew * dis_dst
        int off = atomicAdd(&scnt[c], 1);
        csr[s + off] = make_uint2((unsigned)src, __float_as_uint(v));
    }
}

// t1 row (8 dwords / 32 B): [0..5] = 12 halves of X@W1, [6] = fp32 dis, [7]=0
__global__ void lin1_kernel(const float* __restrict__ X, const float* __restrict__ W1,
                            const float* __restrict__ dis, uint4* __restrict__ t1, int n) {
    int node = (int)((blockIdx.x * (size_t)blockDim.x + threadIdx.x) >> 6);
    int lane = threadIdx.x & 63;
    if (node >= n) return;
    const float* xr = X + (size_t)node * 128;
    float x0 = xr[lane];
    float x1 = xr[lane + 64];
    float res[12];
#pragma unroll
    for (int o = 0; o < 12; o++) {
        float p = x0 * W1[lane * 12 + o] + x1 * W1[(lane + 64) * 12 + o];
#pragma unroll
        for (int off = 32; off > 0; off >>= 1) p += __shfl_xor(p, off, 64);
        res[o] = p;
    }
    if (lane == 0) {
        h8 a, b;
#pragma unroll
        for (int o = 0; o < 8; o++) a[o] = (_Float16)res[o];
#pragma unroll
        for (int o = 0; o < 4; o++) b[o] = (_Float16)res[8 + o];
#pragma unroll
        for (int o = 4; o < 8; o++) b[o] = (_Float16)0.f;
        uint4 ua = __builtin_bit_cast(uint4, a);
        uint4 ub = __builtin_bit_cast(uint4, b);
        ub.z = __float_as_uint(dis[node]);
        ub.w = 0u;
        uint4* dst = t1 + (size_t)node * 2;
        dst[0] = ua;
        dst[1] = ub;
    }
}

// Pull aggregation, 8 lanes per node. csr read-only {src, ew*dis_dst};
// feature rows carry fp16 features + packed fp32 dis of that node, so the
// gather that fetches features also delivers dis_src. ROWW = row in uint4s.
//   norm = csr.y * dis_src;  acc += norm * feat_src
//   v = relu(acc + dis^2 * feat_self + b_this); matvec W_next (or sigmoid)
template <int DIN, int ROWW, int DOUT, bool LAST>
__global__ void agg_kernel(const int* __restrict__ row_ptr, const uint2* __restrict__ csr,
                           const uint4* __restrict__ hin,
                           const float* __restrict__ b_this, const float* __restrict__ W_next,
                           const float* __restrict__ b_next, void* __restrict__ hout_v, int n) {
    int gt   = blockIdx.x * blockDim.x + threadIdx.x;
    int node = gt >> 3;
    int sub  = gt & 7;
    if (node >= n) return;
    int start = row_ptr[node];
    int end   = row_ptr[node + 1];
    float acc[DIN];
#pragma unroll
    for (int d = 0; d < DIN; d++) acc[d] = 0.f;

    for (int e = start + sub; e < end; e += 8) {
        unsigned long long raw =
            __builtin_nontemporal_load((const unsigned long long*)(csr + e));
        int src    = (int)(unsigned)raw;
        float ewdd = __uint_as_float((unsigned)(raw >> 32));
        const uint4* hr = hin + (size_t)src * ROWW;
        if constexpr (DIN == 12) {
            uint4 ua = hr[0], ub = hr[1];
            float norm = ewdd * __uint_as_float(ub.z);
            h8 a = __builtin_bit_cast(h8, ua);
            h8 b = __builtin_bit_cast(h8, ub);
#pragma unroll
            for (int d = 0; d < 8; d++) acc[d] += norm * (float)a[d];
#pragma unroll
            for (int d = 0; d < 4; d++) acc[8 + d] += norm * (float)b[d];
        } else if constexpr (DIN == 6) {
            uint4 u = hr[0];
            float norm = ewdd * __uint_as_float(u.w);
            h8 a = __builtin_bit_cast(h8, u);
#pragma unroll
            for (int d = 0; d < 6; d++) acc[d] += norm * (float)a[d];
        } else {  // DIN == 3
            uint4 u = hr[0];
            float norm = ewdd * __uint_as_float(u.z);
            h8 a = __builtin_bit_cast(h8, u);
#pragma unroll
            for (int d = 0; d < 3; d++) acc[d] += norm * (float)a[d];
        }
    }

#pragma unroll
    for (int d = 0; d < DIN; d++) {
        acc[d] += __shfl_xor(acc[d], 1, 64);
        acc[d] += __shfl_xor(acc[d], 2, 64);
        acc[d] += __shfl_xor(acc[d], 4, 64);
    }

    if (sub == 0) {
        const uint4* hn = hin + (size_t)node * ROWW;
        float v[DIN];
        float dn;
        if constexpr (DIN == 12) {
            uint4 ua = hn[0], ub = hn[1];
            dn = __uint_as_float(ub.z);
            float s2 = dn * dn;
            h8 a = __builtin_bit_cast(h8, ua);
            h8 b = __builtin_bit_cast(h8, ub);
#pragma unroll
            for (int d = 0; d < 8; d++) v[d] = fmaxf(acc[d] + s2 * (float)a[d] + b_this[d], 0.f);
#pragma unroll
            for (int d = 0; d < 4; d++) v[8 + d] = fmaxf(acc[8 + d] + s2 * (float)b[d] + b_this[8 + d], 0.f);
        } else if constexpr (DIN == 6) {
            uint4 u = hn[0];
            dn = __uint_as_float(u.w);
            float s2 = dn * dn;
            h8 a = __builtin_bit_cast(h8, u);
#pragma unroll
            for (int d = 0; d < 6; d++) v[d] = fmaxf(acc[d] + s2 * (float)a[d] + b_this[d], 0.f);
        } else {
            uint4 u = hn[0];
            dn = __uint_as_float(u.z);
            float s2 = dn * dn;
            h8 a = __builtin_bit_cast(h8, u);
#pragma unroll
            for (int d = 0; d < 3; d++) v[d] = fmaxf(acc[d] + s2 * (float)a[d] + b_this[d], 0.f);
        }
        if constexpr (!LAST) {
            float o[DOUT];
#pragma unroll
            for (int oo = 0; oo < DOUT; oo++) {
                float z = 0.f;
#pragma unroll
                for (int d = 0; d < DIN; d++) z += v[d] * W_next[d * DOUT + oo];
                o[oo] = z;
            }
            // pack DOUT halves + own dis into one 16 B row
            h8 w;
#pragma unroll
            for (int oo = 0; oo < 8; oo++) w[oo] = (_Float16)0.f;
#pragma unroll
            for (int oo = 0; oo < DOUT; oo++) w[oo] = (_Float16)o[oo];
            uint4 uw = __builtin_bit_cast(uint4, w);
            if constexpr (DOUT == 6) uw.w = __float_as_uint(dn);
            else                     uw.z = __float_as_uint(dn);
            ((uint4*)hout_v)[node] = uw;
        } else {
            float z = b_next[0];
#pragma unroll
            for (int d = 0; d < DIN; d++) z += v[d] * W_next[d];
            ((float*)hout_v)[node] = 1.0f / (1.0f + expf(-z));
        }
    }
}

// ---------------------------------------------------------------------------
extern "C" void kernel_launch(void* const* d_in, const int* in_sizes, int n_in,
                              void* d_out, int out_size, void* d_ws, size_t ws_size,
                              hipStream_t stream) {
    const float* X  = (const float*)d_in[0];
    const int*   ei = (const int*)d_in[1];
    const float* ew = (const float*)d_in[2];
    const float* W1 = (const float*)d_in[3];
    const float* b1 = (const float*)d_in[4];
    const float* W2 = (const float*)d_in[5];
    const float* b2 = (const float*)d_in[6];
    const float* W3 = (const float*)d_in[7];
    const float* b3 = (const float*)d_in[8];
    const float* Wl = (const float*)d_in[9];
    const float* bl = (const float*)d_in[10];
    float* out = (float*)d_out;

    const int N = in_sizes[0] / 128;
    const int E = in_sizes[1] / 2;
    const int* row = ei;
    const int* col = ei + E;
    const int nfine   = (N + RANGE - 1) >> RSHIFT;
    const int ncoarse = (N + CRANGE - 1) >> CSHIFT;

    char* ws = (char*)d_ws;
    size_t off = 0;
    auto carve = [&](size_t bytes) -> void* {
        void* p = ws + off;
        off += (bytes + 255) & ~(size_t)255;
        return p;
    };
    int*   fcnt    = (int*)  carve((size_t)MAXBUCK * PAD * 4);
    int*   fcur    = (int*)  carve((size_t)MAXBUCK * PAD * 4);
    int*   ccur    = (int*)  carve((size_t)MAXC * PAD * 4);
    int*   cbase   = (int*)  carve((size_t)(MAXC + 1) * 4);
    int*   fbase   = (int*)  carve((size_t)(MAXBUCK + 1) * 4);
    int*   row_ptr = (int*)  carve((size_t)(N + 1) * 4);
    float* dis     = (float*)carve((size_t)N * 4);
    uint2* partA   = (uint2*)carve((size_t)E * 8);
    uint2* partB   = (uint2*)carve((size_t)E * 8);
    // csr reuses partA (dead after fine scatter); t1/t2/t3 reuse partB
    // (dead after bucket_csr; lin1 launches after bucket_csr)
    uint2* csr = partA;
    uint4* t1  = (uint4*)partB;                 // N rows x 2 uint4 (32 B)
    uint4* t2  = t1 + (size_t)N * 2;            // N rows x 1 uint4 (16 B)
    uint4* t3  = t2 + (size_t)N;                // N rows x 1 uint4 (16 B)
    (void)ws_size; (void)n_in; (void)out_size;

    const int bCnt = (E + CH_CNT - 1) / CH_CNT;
    const int bC   = (E + CH_C - 1) / CH_C;        // 3126 coarse-scatter blocks
    const int bF   = (E + CH_F - 1) / CH_F;        // 1563 fine-scatter blocks
    const int bW   = (N + 3) / 4;                  // lin1: wave per node
    const int bA   = ((size_t)N * 8 + 255) / 256;  // agg: 8 lanes per node

    zero_pad_kernel<<<(nfine + 255) / 256, 256, 0, stream>>>(fcnt, nfine);
    count_kernel<<<bCnt, 256, 0, stream>>>(col, fcnt, nfine, E);
    scan_kernel<<<1, 1024, 0, stream>>>(fcnt, fbase, fcur, cbase, ccur, row_ptr,
                                        nfine, ncoarse, N, E);
    coarse_scatter_kernel<<<bC, 256, 0, stream>>>(row, col, ew, ccur, partA, ncoarse, E);
    fine_scatter_kernel<<<bF, 256, 0, stream>>>(partA, cbase, fcur, partB, nfine, ncoarse, E);
    bucket_csr_kernel<<<nfine, 256, 0, stream>>>(partB, fbase, row_ptr, dis, csr, N);
    lin1_kernel<<<bW, 256, 0, stream>>>(X, W1, dis, t1, N);
    agg_kernel<12, 2, 6, false><<<bA, 256, 0, stream>>>(row_ptr, csr, t1, b1, W2, nullptr, t2, N);
    agg_kernel< 6, 1, 3, false><<<bA, 256, 0, stream>>>(row_ptr, csr, t2, b2, W3, nullptr, t3, N);
    agg_kernel< 3, 1, 1, true ><<<bA, 256, 0, stream>>>(row_ptr, csr, t3, b3, Wl, bl, out, N);
}

// Round 9
// 609.115 us; speedup vs baseline: 1.1071x; 1.0604x over previous
//
#include <hip/hip_runtime.h>
#include <cstdint>
#include <cstddef>

#define RANGE    128       // nodes per fine bucket
#define RSHIFT   7
#define MAXBUCK  800       // >= ceil(N/RANGE); N=100K -> 782
#define CSHIFT   12        // nodes per coarse bucket = 4096
#define CRANGE   4096
#define MAXC     32        // >= ceil(N/CRANGE); N=100K -> 25
#define FPB      32        // fine buckets per coarse bucket
#define CH_CNT   8192      // edges per block, count pass
#define CH_SC    4096      // edges per block, scatter passes
#define EPT      16        // CH_SC / 256
#define PAD      16        // pad global counters to one 64B line each

typedef _Float16 h8 __attribute__((ext_vector_type(8)));

// ---------------------------------------------------------------------------
__global__ void zero_pad_kernel(int* __restrict__ p, int n) {
    int i = blockIdx.x * blockDim.x + threadIdx.x;
    if (i < n) p[i * PAD] = 0;
}

// fine histogram (782 buckets) of col>>7; per-block LDS, merged w/ global atomics
__global__ void count_kernel(const int* __restrict__ col, int* __restrict__ fcnt,
                             int nfine, int E) {
    __shared__ int lcnt[MAXBUCK];
    int tid = threadIdx.x;
    for (int i = tid; i < nfine; i += blockDim.x) lcnt[i] = 0;
    __syncthreads();
    int base = blockIdx.x * CH_CNT;
    int end  = min(E, base + CH_CNT);
    for (int e = base + tid; e < end; e += blockDim.x)
        atomicAdd(&lcnt[col[e] >> RSHIFT], 1);
    __syncthreads();
    for (int i = tid; i < nfine; i += blockDim.x)
        if (lcnt[i]) atomicAdd(&fcnt[i * PAD], lcnt[i]);
}

// scan fine counts -> fine bases/cursors; derive coarse bases/cursors
__global__ void scan_kernel(const int* __restrict__ fcnt, int* __restrict__ fbase,
                            int* __restrict__ fcur, int* __restrict__ cbase,
                            int* __restrict__ ccur, int* __restrict__ row_ptr,
                            int nfine, int ncoarse, int N, int E) {
    __shared__ int lds[1024];
    int T = threadIdx.x;
    int s = (T < nfine) ? fcnt[T * PAD] : 0;
    lds[T] = s;
    __syncthreads();
    for (int off = 1; off < 1024; off <<= 1) {
        int v = (T >= off) ? lds[T - off] : 0;
        __syncthreads();
        lds[T] += v;
        __syncthreads();
    }
    int excl = lds[T] - s;
    if (T < nfine) { fbase[T] = excl; fcur[T * PAD] = excl; }
    if ((T & (FPB - 1)) == 0 && (T >> 5) < ncoarse) {
        cbase[T >> 5] = excl;
        ccur[(T >> 5) * PAD] = excl;
    }
    if (T == 0) { fbase[nfine] = E; cbase[ncoarse] = E; row_ptr[N] = E; }
}

// coarse scatter with LDS counting-sort staging: records leave the block
// bucket-sorted, so global stores are fully coalesced dense segments.
// record = {row | col_low12<<17, ew}
__global__ void coarse_scatter_kernel(const int* __restrict__ row, const int* __restrict__ col,
                                      const float* __restrict__ ew, int* __restrict__ ccur,
                                      uint2* __restrict__ partA, int ncoarse, int E) {
    __shared__ uint2 stage[CH_SC];
    __shared__ unsigned char sb[CH_SC];
    __shared__ int lcnt[MAXC], lofs[MAXC], gofs[MAXC];
    __shared__ int total_s;
    int tid = threadIdx.x;
    if (tid < MAXC) lcnt[tid] = 0;
    __syncthreads();
    int base = blockIdx.x * CH_SC;
    int cnt  = min(E - base, CH_SC);

    uint2 rec[EPT]; int rnk[EPT]; int bb[EPT];
#pragma unroll
    for (int k = 0; k < EPT; k++) {
        int idx = tid + (k << 8);
        if (idx < cnt) {
            int e = base + idx;
            int c = col[e];
            int b = c >> CSHIFT;
            bb[k]  = b;
            rec[k] = make_uint2((unsigned)row[e] | ((unsigned)(c & (CRANGE - 1)) << 17),
                                __float_as_uint(ew[e]));
            rnk[k] = atomicAdd(&lcnt[b], 1);   // one LDS atomic per edge; rank kept in regs
        }
    }
    __syncthreads();
    if (tid == 0) {  // 25-entry serial scan
        int run = 0;
        for (int i = 0; i < ncoarse; i++) { lofs[i] = run; run += lcnt[i]; }
        total_s = run;
    }
    __syncthreads();
    if (tid < ncoarse) {
        int c = lcnt[tid];
        if (c) {
            int g = atomicAdd(&ccur[tid * PAD], c);
            gofs[tid] = g - lofs[tid];
        }
    }
#pragma unroll
    for (int k = 0; k < EPT; k++) {
        int idx = tid + (k << 8);
        if (idx < cnt) {
            int p = lofs[bb[k]] + rnk[k];
            stage[p] = rec[k];
            sb[p] = (unsigned char)bb[k];
        }
    }
    __syncthreads();
    int total = total_s;
    for (int i = tid; i < total; i += 256)   // dense, coalesced copy-out
        partA[gofs[sb[i]] + i] = stage[i];
}

// fine scatter (same staging scheme): partA (coarsely sorted) -> partB grouped
// by 128-node fine bucket.  output record = {row | dst_local<<17, ew}
__global__ void fine_scatter_kernel(const uint2* __restrict__ partA, const int* __restrict__ cbase,
                                    int* __restrict__ fcur, uint2* __restrict__ partB,
                                    int nfine, int ncoarse, int E) {
    __shared__ uint2 stage[CH_SC];
    __shared__ unsigned short sb[CH_SC];
    __shared__ int lcnt[MAXBUCK], lofs[MAXBUCK], gofs[MAXBUCK];
    __shared__ int tmp[256];
    __shared__ int scb[MAXC + 1];
    __shared__ int rlo_s, total_s;
    int tid = threadIdx.x;
    int base = blockIdx.x * CH_SC;
    int cnt  = min(E - base, CH_SC);
    if (tid <= ncoarse) scb[tid] = cbase[tid];
    for (int i = tid; i < nfine; i += 256) lcnt[i] = 0;
    if (tid == 0) {
        int r = 0;
        while (r < ncoarse - 1 && cbase[r + 1] <= base) ++r;
        rlo_s = r;
    }
    __syncthreads();
    int rlo = rlo_s;

    uint2 rec[EPT]; int rnk[EPT]; int ff[EPT];
#pragma unroll
    for (int k = 0; k < EPT; k++) {
        int idx = tid + (k << 8);
        if (idx < cnt) {
            int e = base + idx;
            uint2 v = partA[e];
            int r = rlo;
            while (e >= scb[r + 1]) ++r;   // short walk: chunk spans ~2 regions
            int col12 = (int)((v.x >> 17) & (CRANGE - 1));
            int f = (r << 5) | (col12 >> RSHIFT);
            ff[k]  = f;
            rec[k] = make_uint2((v.x & 0x1FFFFu) | ((unsigned)(col12 & (RANGE - 1)) << 17), v.y);
            rnk[k] = atomicAdd(&lcnt[f], 1);
        }
    }
    __syncthreads();
    {   // parallel exclusive scan of lcnt[0..nfine) -> lofs
        const int Cc = (nfine + 255) >> 8;   // 4 counters per thread
        int b0 = tid * Cc;
        int s = 0;
        for (int i = 0; i < Cc; i++) {
            int idx = b0 + i;
            if (idx < nfine) s += lcnt[idx];
        }
        tmp[tid] = s;
        __syncthreads();
        for (int off = 1; off < 256; off <<= 1) {
            int v = (tid >= off) ? tmp[tid - off] : 0;
            __syncthreads();
            tmp[tid] += v;
            __syncthreads();
        }
        int run = tmp[tid] - s;
        for (int i = 0; i < Cc; i++) {
            int idx = b0 + i;
            if (idx < nfine) { lofs[idx] = run; run += lcnt[idx]; }
        }
        if (tid == 255) total_s = tmp[255];
    }
    __syncthreads();
    for (int i = tid; i < nfine; i += 256) {
        int c = lcnt[i];
        if (c) {
            int g = atomicAdd(&fcur[i * PAD], c);
            gofs[i] = g - lofs[i];
        }
    }
#pragma unroll
    for (int k = 0; k < EPT; k++) {
        int idx = tid + (k << 8);
        if (idx < cnt) {
            int p = lofs[ff[k]] + rnk[k];
            stage[p] = rec[k];
            sb[p] = (unsigned short)ff[k];
        }
    }
    __syncthreads();
    int total = total_s;
    for (int i = tid; i < total; i += 256)   // dense, coalesced copy-out
        partB[gofs[sb[i]] + i] = stage[i];
}

// one block per fine bucket: per-node CSR + row_ptr + dis, all in LDS.
// csr.y = ew * dis_dst (dst-side prenorm, local dis only); src-side dis
// factor travels packed inside the feature rows.
__global__ void bucket_csr_kernel(const uint2* __restrict__ part, const int* __restrict__ bbase,
                                  int* __restrict__ row_ptr, float* __restrict__ dis,
                                  uint2* __restrict__ csr, int N) {
    __shared__ int   scnt[RANGE];
    __shared__ int   sscan[RANGE];
    __shared__ float sdeg[RANGE];
    __shared__ float sdis[RANGE];
    int b = blockIdx.x, tid = threadIdx.x;
    int s = bbase[b], t = bbase[b + 1];
    if (tid < RANGE) { scnt[tid] = 0; sdeg[tid] = 1.0f; }  // self-loop weight
    __syncthreads();
    for (int e = s + tid; e < t; e += blockDim.x) {
        uint2 r = part[e];
        int c = (r.x >> 17) & (RANGE - 1);
        atomicAdd(&scnt[c], 1);
        atomicAdd(&sdeg[c], __uint_as_float(r.y));
    }
    __syncthreads();
    int cnt_t = 0;
    if (tid < RANGE) { cnt_t = scnt[tid]; sscan[tid] = cnt_t; }
    __syncthreads();
    for (int off = 1; off < RANGE; off <<= 1) {
        int v = 0;
        if (tid < RANGE && tid >= off) v = sscan[tid - off];
        __syncthreads();
        if (tid < RANGE) sscan[tid] += v;
        __syncthreads();
    }
    if (tid < RANGE) {
        int excl = sscan[tid] - cnt_t;
        int node = b * RANGE + tid;
        float dn = rsqrtf(sdeg[tid]);
        sdis[tid] = dn;
        if (node < N) {
            row_ptr[node] = s + excl;
            dis[node] = dn;
        }
        scnt[tid] = excl;  // reuse as within-bucket cursor
    }
    __syncthreads();
    for (int e = s + tid; e < t; e += blockDim.x) {
        uint2 r = part[e];
        int c   = (r.x >> 17) & (RANGE - 1);
        int src = (int)(r.x & 0x1FFFFu);
        float v = sdis[c] * __uint_as_float(r.y);   // ew * dis_dst
        int off = atomicAdd(&scnt[c], 1);
        csr[s + off] = make_uint2((unsigned)src, __float_as_uint(v));
    }
}

// t1 row (8 dwords / 32 B): [0..5] = 12 halves of X@W1, [6] = fp32 dis, [7]=0
__global__ void lin1_kernel(const float* __restrict__ X, const float* __restrict__ W1,
                            const float* __restrict__ dis, uint4* __restrict__ t1, int n) {
    int node = (int)((blockIdx.x * (size_t)blockDim.x + threadIdx.x) >> 6);
    int lane = threadIdx.x & 63;
    if (node >= n) return;
    const float* xr = X + (size_t)node * 128;
    float x0 = xr[lane];
    float x1 = xr[lane + 64];
    float res[12];
#pragma unroll
    for (int o = 0; o < 12; o++) {
        float p = x0 * W1[lane * 12 + o] + x1 * W1[(lane + 64) * 12 + o];
#pragma unroll
        for (int off = 32; off > 0; off >>= 1) p += __shfl_xor(p, off, 64);
        res[o] = p;
    }
    if (lane == 0) {
        h8 a, b;
#pragma unroll
        for (int o = 0; o < 8; o++) a[o] = (_Float16)res[o];
#pragma unroll
        for (int o = 0; o < 4; o++) b[o] = (_Float16)res[8 + o];
#pragma unroll
        for (int o = 4; o < 8; o++) b[o] = (_Float16)0.f;
        uint4 ua = __builtin_bit_cast(uint4, a);
        uint4 ub = __builtin_bit_cast(uint4, b);
        ub.z = __float_as_uint(dis[node]);
        ub.w = 0u;
        uint4* dst = t1 + (size_t)node * 2;
        dst[0] = ua;
        dst[1] = ub;
    }
}

// Pull aggregation, 8 lanes per node. csr read-only {src, ew*dis_dst};
// feature rows carry fp16 features + packed fp32 dis of that node.
template <int DIN, int ROWW, int DOUT, bool LAST>
__global__ void agg_kernel(const int* __restrict__ row_ptr, const uint2* __restrict__ csr,
                           const uint4* __restrict__ hin,
                           const float* __restrict__ b_this, const float* __restrict__ W_next,
                           const float* __restrict__ b_next, void* __restrict__ hout_v, int n) {
    int gt   = blockIdx.x * blockDim.x + threadIdx.x;
    int node = gt >> 3;
    int sub  = gt & 7;
    if (node >= n) return;
    int start = row_ptr[node];
    int end   = row_ptr[node + 1];
    float acc[DIN];
#pragma unroll
    for (int d = 0; d < DIN; d++) acc[d] = 0.f;

    for (int e = start + sub; e < end; e += 8) {
        unsigned long long raw =
            __builtin_nontemporal_load((const unsigned long long*)(csr + e));
        int src    = (int)(unsigned)raw;
        float ewdd = __uint_as_float((unsigned)(raw >> 32));
        const uint4* hr = hin + (size_t)src * ROWW;
        if constexpr (DIN == 12) {
            uint4 ua = hr[0], ub = hr[1];
            float norm = ewdd * __uint_as_float(ub.z);
            h8 a = __builtin_bit_cast(h8, ua);
            h8 b = __builtin_bit_cast(h8, ub);
#pragma unroll
            for (int d = 0; d < 8; d++) acc[d] += norm * (float)a[d];
#pragma unroll
            for (int d = 0; d < 4; d++) acc[8 + d] += norm * (float)b[d];
        } else if constexpr (DIN == 6) {
            uint4 u = hr[0];
            float norm = ewdd * __uint_as_float(u.w);
            h8 a = __builtin_bit_cast(h8, u);
#pragma unroll
            for (int d = 0; d < 6; d++) acc[d] += norm * (float)a[d];
        } else {  // DIN == 3
            uint4 u = hr[0];
            float norm = ewdd * __uint_as_float(u.z);
            h8 a = __builtin_bit_cast(h8, u);
#pragma unroll
            for (int d = 0; d < 3; d++) acc[d] += norm * (float)a[d];
        }
    }

#pragma unroll
    for (int d = 0; d < DIN; d++) {
        acc[d] += __shfl_xor(acc[d], 1, 64);
        acc[d] += __shfl_xor(acc[d], 2, 64);
        acc[d] += __shfl_xor(acc[d], 4, 64);
    }

    if (sub == 0) {
        const uint4* hn = hin + (size_t)node * ROWW;
        float v[DIN];
        float dn;
        if constexpr (DIN == 12) {
            uint4 ua = hn[0], ub = hn[1];
            dn = __uint_as_float(ub.z);
            float s2 = dn * dn;
            h8 a = __builtin_bit_cast(h8, ua);
            h8 b = __builtin_bit_cast(h8, ub);
#pragma unroll
            for (int d = 0; d < 8; d++) v[d] = fmaxf(acc[d] + s2 * (float)a[d] + b_this[d], 0.f);
#pragma unroll
            for (int d = 0; d < 4; d++) v[8 + d] = fmaxf(acc[8 + d] + s2 * (float)b[d] + b_this[8 + d], 0.f);
        } else if constexpr (DIN == 6) {
            uint4 u = hn[0];
            dn = __uint_as_float(u.w);
            float s2 = dn * dn;
            h8 a = __builtin_bit_cast(h8, u);
#pragma unroll
            for (int d = 0; d < 6; d++) v[d] = fmaxf(acc[d] + s2 * (float)a[d] + b_this[d], 0.f);
        } else {
            uint4 u = hn[0];
            dn = __uint_as_float(u.z);
            float s2 = dn * dn;
            h8 a = __builtin_bit_cast(h8, u);
#pragma unroll
            for (int d = 0; d < 3; d++) v[d] = fmaxf(acc[d] + s2 * (float)a[d] + b_this[d], 0.f);
        }
        if constexpr (!LAST) {
            float o[DOUT];
#pragma unroll
            for (int oo = 0; oo < DOUT; oo++) {
                float z = 0.f;
#pragma unroll
                for (int d = 0; d < DIN; d++) z += v[d] * W_next[d * DOUT + oo];
                o[oo] = z;
            }
            h8 w;
#pragma unroll
            for (int oo = 0; oo < 8; oo++) w[oo] = (_Float16)0.f;
#pragma unroll
            for (int oo = 0; oo < DOUT; oo++) w[oo] = (_Float16)o[oo];
            uint4 uw = __builtin_bit_cast(uint4, w);
            if constexpr (DOUT == 6) uw.w = __float_as_uint(dn);
            else                     uw.z = __float_as_uint(dn);
            ((uint4*)hout_v)[node] = uw;
        } else {
            float z = b_next[0];
#pragma unroll
            for (int d = 0; d < DIN; d++) z += v[d] * W_next[d];
            ((float*)hout_v)[node] = 1.0f / (1.0f + expf(-z));
        }
    }
}

// ---------------------------------------------------------------------------
extern "C" void kernel_launch(void* const* d_in, const int* in_sizes, int n_in,
                              void* d_out, int out_size, void* d_ws, size_t ws_size,
                              hipStream_t stream) {
    const float* X  = (const float*)d_in[0];
    const int*   ei = (const int*)d_in[1];
    const float* ew = (const float*)d_in[2];
    const float* W1 = (const float*)d_in[3];
    const float* b1 = (const float*)d_in[4];
    const float* W2 = (const float*)d_in[5];
    const float* b2 = (const float*)d_in[6];
    const float* W3 = (const float*)d_in[7];
    const float* b3 = (const float*)d_in[8];
    const float* Wl = (const float*)d_in[9];
    const float* bl = (const float*)d_in[10];
    float* out = (float*)d_out;

    const int N = in_sizes[0] / 128;
    const int E = in_sizes[1] / 2;
    const int* row = ei;
    const int* col = ei + E;
    const int nfine   = (N + RANGE - 1) >> RSHIFT;
    const int ncoarse = (N + CRANGE - 1) >> CSHIFT;

    char* ws = (char*)d_ws;
    size_t off = 0;
    auto carve = [&](size_t bytes) -> void* {
        void* p = ws + off;
        off += (bytes + 255) & ~(size_t)255;
        return p;
    };
    int*   fcnt    = (int*)  carve((size_t)MAXBUCK * PAD * 4);
    int*   fcur    = (int*)  carve((size_t)MAXBUCK * PAD * 4);
    int*   ccur    = (int*)  carve((size_t)MAXC * PAD * 4);
    int*   cbase   = (int*)  carve((size_t)(MAXC + 1) * 4);
    int*   fbase   = (int*)  carve((size_t)(MAXBUCK + 1) * 4);
    int*   row_ptr = (int*)  carve((size_t)(N + 1) * 4);
    float* dis     = (float*)carve((size_t)N * 4);
    uint2* partA   = (uint2*)carve((size_t)E * 8);
    uint2* partB   = (uint2*)carve((size_t)E * 8);
    // csr reuses partA (dead after fine scatter); t1/t2/t3 reuse partB
    uint2* csr = partA;
    uint4* t1  = (uint4*)partB;                 // N rows x 2 uint4 (32 B)
    uint4* t2  = t1 + (size_t)N * 2;            // N rows x 1 uint4 (16 B)
    uint4* t3  = t2 + (size_t)N;                // N rows x 1 uint4 (16 B)
    (void)ws_size; (void)n_in; (void)out_size;

    const int bCnt = (E + CH_CNT - 1) / CH_CNT;
    const int bSc  = (E + CH_SC - 1) / CH_SC;      // 1563 scatter blocks
    const int bW   = (N + 3) / 4;                  // lin1: wave per node
    const int bA   = ((size_t)N * 8 + 255) / 256;  // agg: 8 lanes per node

    zero_pad_kernel<<<(nfine + 255) / 256, 256, 0, stream>>>(fcnt, nfine);
    count_kernel<<<bCnt, 256, 0, stream>>>(col, fcnt, nfine, E);
    scan_kernel<<<1, 1024, 0, stream>>>(fcnt, fbase, fcur, cbase, ccur, row_ptr,
                                        nfine, ncoarse, N, E);
    coarse_scatter_kernel<<<bSc, 256, 0, stream>>>(row, col, ew, ccur, partA, ncoarse, E);
    fine_scatter_kernel<<<bSc, 256, 0, stream>>>(partA, cbase, fcur, partB, nfine, ncoarse, E);
    bucket_csr_kernel<<<nfine, 256, 0, stream>>>(partB, fbase, row_ptr, dis, csr, N);
    lin1_kernel<<<bW, 256, 0, stream>>>(X, W1, dis, t1, N);
    agg_kernel<12, 2, 6, false><<<bA, 256, 0, stream>>>(row_ptr, csr, t1, b1, W2, nullptr, t2, N);
    agg_kernel< 6, 1, 3, false><<<bA, 256, 0, stream>>>(row_ptr, csr, t2, b2, W3, nullptr, t3, N);
    agg_kernel< 3, 1, 1, true ><<<bA, 256, 0, stream>>>(row_ptr, csr, t3, b3, Wl, bl, out, N);
}

// Round 10
// 557.224 us; speedup vs baseline: 1.2102x; 1.0931x over previous
//
#include <hip/hip_runtime.h>
#include <cstdint>
#include <cstddef>

#define RANGE    128       // nodes per fine bucket
#define RSHIFT   7
#define MAXBUCK  800       // >= ceil(N/RANGE); N=100K -> 782
#define CSHIFT   12        // nodes per coarse bucket = 4096
#define CRANGE   4096
#define MAXC     32        // >= ceil(N/CRANGE); N=100K -> 25
#define FPB      32        // fine buckets per coarse bucket
#define CH_CNT   8192      // edges per block, count pass
#define CH_SC    4096      // edges per block, scatter passes
#define EPT      16        // CH_SC / 256
#define PAD      16        // pad global counters to one 64B line each
#define WSTR     132       // LDS stride for transposed W1 (16B-aligned, rotates banks)

typedef _Float16 h8 __attribute__((ext_vector_type(8)));

// ---------------------------------------------------------------------------
__global__ void zero_pad_kernel(int* __restrict__ p, int n) {
    int i = blockIdx.x * blockDim.x + threadIdx.x;
    if (i < n) p[i * PAD] = 0;
}

// fine histogram (782 buckets) of col>>7; per-block LDS, merged w/ global atomics
__global__ void count_kernel(const int* __restrict__ col, int* __restrict__ fcnt,
                             int nfine, int E) {
    __shared__ int lcnt[MAXBUCK];
    int tid = threadIdx.x;
    for (int i = tid; i < nfine; i += blockDim.x) lcnt[i] = 0;
    __syncthreads();
    int base = blockIdx.x * CH_CNT;
    int end  = min(E, base + CH_CNT);
    for (int e = base + tid; e < end; e += blockDim.x)
        atomicAdd(&lcnt[col[e] >> RSHIFT], 1);
    __syncthreads();
    for (int i = tid; i < nfine; i += blockDim.x)
        if (lcnt[i]) atomicAdd(&fcnt[i * PAD], lcnt[i]);
}

// scan fine counts -> fine bases/cursors; derive coarse bases/cursors
__global__ void scan_kernel(const int* __restrict__ fcnt, int* __restrict__ fbase,
                            int* __restrict__ fcur, int* __restrict__ cbase,
                            int* __restrict__ ccur, int* __restrict__ row_ptr,
                            int nfine, int ncoarse, int N, int E) {
    __shared__ int lds[1024];
    int T = threadIdx.x;
    int s = (T < nfine) ? fcnt[T * PAD] : 0;
    lds[T] = s;
    __syncthreads();
    for (int off = 1; off < 1024; off <<= 1) {
        int v = (T >= off) ? lds[T - off] : 0;
        __syncthreads();
        lds[T] += v;
        __syncthreads();
    }
    int excl = lds[T] - s;
    if (T < nfine) { fbase[T] = excl; fcur[T * PAD] = excl; }
    if ((T & (FPB - 1)) == 0 && (T >> 5) < ncoarse) {
        cbase[T >> 5] = excl;
        ccur[(T >> 5) * PAD] = excl;
    }
    if (T == 0) { fbase[nfine] = E; cbase[ncoarse] = E; row_ptr[N] = E; }
}

// coarse scatter with LDS counting-sort staging: records leave the block
// bucket-sorted, so global stores are fully coalesced dense segments.
// record = {row | col_low12<<17, ew}
__global__ void coarse_scatter_kernel(const int* __restrict__ row, const int* __restrict__ col,
                                      const float* __restrict__ ew, int* __restrict__ ccur,
                                      uint2* __restrict__ partA, int ncoarse, int E) {
    __shared__ uint2 stage[CH_SC];
    __shared__ unsigned char sb[CH_SC];
    __shared__ int lcnt[MAXC], lofs[MAXC], gofs[MAXC];
    __shared__ int total_s;
    int tid = threadIdx.x;
    if (tid < MAXC) lcnt[tid] = 0;
    __syncthreads();
    int base = blockIdx.x * CH_SC;
    int cnt  = min(E - base, CH_SC);

    uint2 rec[EPT]; int rnk[EPT]; int bb[EPT];
#pragma unroll
    for (int k = 0; k < EPT; k++) {
        int idx = tid + (k << 8);
        if (idx < cnt) {
            int e = base + idx;
            int c = col[e];
            int b = c >> CSHIFT;
            bb[k]  = b;
            rec[k] = make_uint2((unsigned)row[e] | ((unsigned)(c & (CRANGE - 1)) << 17),
                                __float_as_uint(ew[e]));
            rnk[k] = atomicAdd(&lcnt[b], 1);   // one LDS atomic per edge; rank kept in regs
        }
    }
    __syncthreads();
    if (tid == 0) {  // 25-entry serial scan
        int run = 0;
        for (int i = 0; i < ncoarse; i++) { lofs[i] = run; run += lcnt[i]; }
        total_s = run;
    }
    __syncthreads();
    if (tid < ncoarse) {
        int c = lcnt[tid];
        if (c) {
            int g = atomicAdd(&ccur[tid * PAD], c);
            gofs[tid] = g - lofs[tid];
        }
    }
#pragma unroll
    for (int k = 0; k < EPT; k++) {
        int idx = tid + (k << 8);
        if (idx < cnt) {
            int p = lofs[bb[k]] + rnk[k];
            stage[p] = rec[k];
            sb[p] = (unsigned char)bb[k];
        }
    }
    __syncthreads();
    int total = total_s;
    for (int i = tid; i < total; i += 256)   // dense, coalesced copy-out
        partA[gofs[sb[i]] + i] = stage[i];
}

// fine scatter (same staging scheme): partA (coarsely sorted) -> partB grouped
// by 128-node fine bucket.  output record = {row | dst_local<<17, ew}
__global__ void fine_scatter_kernel(const uint2* __restrict__ partA, const int* __restrict__ cbase,
                                    int* __restrict__ fcur, uint2* __restrict__ partB,
                                    int nfine, int ncoarse, int E) {
    __shared__ uint2 stage[CH_SC];
    __shared__ unsigned short sb[CH_SC];
    __shared__ int lcnt[MAXBUCK], lofs[MAXBUCK], gofs[MAXBUCK];
    __shared__ int tmp[256];
    __shared__ int scb[MAXC + 1];
    __shared__ int rlo_s, total_s;
    int tid = threadIdx.x;
    int base = blockIdx.x * CH_SC;
    int cnt  = min(E - base, CH_SC);
    if (tid <= ncoarse) scb[tid] = cbase[tid];
    for (int i = tid; i < nfine; i += 256) lcnt[i] = 0;
    if (tid == 0) {
        int r = 0;
        while (r < ncoarse - 1 && cbase[r + 1] <= base) ++r;
        rlo_s = r;
    }
    __syncthreads();
    int rlo = rlo_s;

    uint2 rec[EPT]; int rnk[EPT]; int ff[EPT];
#pragma unroll
    for (int k = 0; k < EPT; k++) {
        int idx = tid + (k << 8);
        if (idx < cnt) {
            int e = base + idx;
            uint2 v = partA[e];
            int r = rlo;
            while (e >= scb[r + 1]) ++r;   // short walk: chunk spans ~2 regions
            int col12 = (int)((v.x >> 17) & (CRANGE - 1));
            int f = (r << 5) | (col12 >> RSHIFT);
            ff[k]  = f;
            rec[k] = make_uint2((v.x & 0x1FFFFu) | ((unsigned)(col12 & (RANGE - 1)) << 17), v.y);
            rnk[k] = atomicAdd(&lcnt[f], 1);
        }
    }
    __syncthreads();
    {   // parallel exclusive scan of lcnt[0..nfine) -> lofs
        const int Cc = (nfine + 255) >> 8;   // 4 counters per thread
        int b0 = tid * Cc;
        int s = 0;
        for (int i = 0; i < Cc; i++) {
            int idx = b0 + i;
            if (idx < nfine) s += lcnt[idx];
        }
        tmp[tid] = s;
        __syncthreads();
        for (int off = 1; off < 256; off <<= 1) {
            int v = (tid >= off) ? tmp[tid - off] : 0;
            __syncthreads();
            tmp[tid] += v;
            __syncthreads();
        }
        int run = tmp[tid] - s;
        for (int i = 0; i < Cc; i++) {
            int idx = b0 + i;
            if (idx < nfine) { lofs[idx] = run; run += lcnt[idx]; }
        }
        if (tid == 255) total_s = tmp[255];
    }
    __syncthreads();
    for (int i = tid; i < nfine; i += 256) {
        int c = lcnt[i];
        if (c) {
            int g = atomicAdd(&fcur[i * PAD], c);
            gofs[i] = g - lofs[i];
        }
    }
#pragma unroll
    for (int k = 0; k < EPT; k++) {
        int idx = tid + (k << 8);
        if (idx < cnt) {
            int p = lofs[ff[k]] + rnk[k];
            stage[p] = rec[k];
            sb[p] = (unsigned short)ff[k];
        }
    }
    __syncthreads();
    int total = total_s;
    for (int i = tid; i < total; i += 256)   // dense, coalesced copy-out
        partB[gofs[sb[i]] + i] = stage[i];
}

// one block per fine bucket: per-node CSR + row_ptr + dis, all in LDS.
// csr.y = ew * dis_dst (dst-side prenorm, local dis only); src-side dis
// factor travels packed inside the feature rows.
__global__ void bucket_csr_kernel(const uint2* __restrict__ part, const int* __restrict__ bbase,
                                  int* __restrict__ row_ptr, float* __restrict__ dis,
                                  uint2* __restrict__ csr, int N) {
    __shared__ int   scnt[RANGE];
    __shared__ int   sscan[RANGE];
    __shared__ float sdeg[RANGE];
    __shared__ float sdis[RANGE];
    int b = blockIdx.x, tid = threadIdx.x;
    int s = bbase[b], t = bbase[b + 1];
    if (tid < RANGE) { scnt[tid] = 0; sdeg[tid] = 1.0f; }  // self-loop weight
    __syncthreads();
    for (int e = s + tid; e < t; e += blockDim.x) {
        uint2 r = part[e];
        int c = (r.x >> 17) & (RANGE - 1);
        atomicAdd(&scnt[c], 1);
        atomicAdd(&sdeg[c], __uint_as_float(r.y));
    }
    __syncthreads();
    int cnt_t = 0;
    if (tid < RANGE) { cnt_t = scnt[tid]; sscan[tid] = cnt_t; }
    __syncthreads();
    for (int off = 1; off < RANGE; off <<= 1) {
        int v = 0;
        if (tid < RANGE && tid >= off) v = sscan[tid - off];
        __syncthreads();
        if (tid < RANGE) sscan[tid] += v;
        __syncthreads();
    }
    if (tid < RANGE) {
        int excl = sscan[tid] - cnt_t;
        int node = b * RANGE + tid;
        float dn = rsqrtf(sdeg[tid]);
        sdis[tid] = dn;
        if (node < N) {
            row_ptr[node] = s + excl;
            dis[node] = dn;
        }
        scnt[tid] = excl;  // reuse as within-bucket cursor
    }
    __syncthreads();
    for (int e = s + tid; e < t; e += blockDim.x) {
        uint2 r = part[e];
        int c   = (r.x >> 17) & (RANGE - 1);
        int src = (int)(r.x & 0x1FFFFu);
        float v = sdis[c] * __uint_as_float(r.y);   // ew * dis_dst
        int off = atomicAdd(&scnt[c], 1);
        csr[s + off] = make_uint2((unsigned)src, __float_as_uint(v));
    }
}

// t1 = fp16(X @ W1) + packed dis.  8 lanes per node: each lane owns 16 of the
// 128 inputs (4 coalesced float4 loads), W1 transposed in LDS (stride 132),
// 192 independent FMAs per lane, then 3-step shuffle reduction (was 6-step
// wave-wide chains — the R9 bottleneck).  t1 row (32 B): 12 halves + fp32 dis.
__global__ void lin1_kernel(const float* __restrict__ X, const float* __restrict__ W1,
                            const float* __restrict__ dis, uint4* __restrict__ t1, int n) {
    __shared__ float w1t[12 * WSTR];
    int tid = threadIdx.x;
    for (int i = tid; i < 128 * 12; i += 256) {
        int k = i / 12, o = i - k * 12;
        w1t[o * WSTR + k] = W1[i];
    }
    __syncthreads();
    int gt   = blockIdx.x * 256 + tid;
    int node = gt >> 3;
    int sub  = gt & 7;
    if (node >= n) return;

    const float4* xp = (const float4*)(X + (size_t)node * 128 + sub * 16);
    float4 x0 = xp[0], x1 = xp[1], x2 = xp[2], x3 = xp[3];

    float res[12];
#pragma unroll
    for (int o = 0; o < 12; o++) {
        const float4* wp = (const float4*)(w1t + o * WSTR + sub * 16);
        float4 w0 = wp[0], w1v = wp[1], w2 = wp[2], w3 = wp[3];
        float s;
        s  = x0.x * w0.x + x0.y * w0.y + x0.z * w0.z + x0.w * w0.w;
        s += x1.x * w1v.x + x1.y * w1v.y + x1.z * w1v.z + x1.w * w1v.w;
        s += x2.x * w2.x + x2.y * w2.y + x2.z * w2.z + x2.w * w2.w;
        s += x3.x * w3.x + x3.y * w3.y + x3.z * w3.z + x3.w * w3.w;
        res[o] = s;
    }
#pragma unroll
    for (int o = 0; o < 12; o++) {
        res[o] += __shfl_xor(res[o], 1, 64);
        res[o] += __shfl_xor(res[o], 2, 64);
        res[o] += __shfl_xor(res[o], 4, 64);
    }
    if (sub == 0) {
        h8 a, b;
#pragma unroll
        for (int o = 0; o < 8; o++) a[o] = (_Float16)res[o];
#pragma unroll
        for (int o = 0; o < 4; o++) b[o] = (_Float16)res[8 + o];
#pragma unroll
        for (int o = 4; o < 8; o++) b[o] = (_Float16)0.f;
        uint4 ua = __builtin_bit_cast(uint4, a);
        uint4 ub = __builtin_bit_cast(uint4, b);
        ub.z = __float_as_uint(dis[node]);
        ub.w = 0u;
        uint4* dst = t1 + (size_t)node * 2;
        dst[0] = ua;
        dst[1] = ub;
    }
}

// Pull aggregation, 8 lanes per node. csr read-only {src, ew*dis_dst};
// feature rows carry fp16 features + packed fp32 dis of that node.
template <int DIN, int ROWW, int DOUT, bool LAST>
__global__ void agg_kernel(const int* __restrict__ row_ptr, const uint2* __restrict__ csr,
                           const uint4* __restrict__ hin,
                           const float* __restrict__ b_this, const float* __restrict__ W_next,
                           const float* __restrict__ b_next, void* __restrict__ hout_v, int n) {
    int gt   = blockIdx.x * blockDim.x + threadIdx.x;
    int node = gt >> 3;
    int sub  = gt & 7;
    if (node >= n) return;
    int start = row_ptr[node];
    int end   = row_ptr[node + 1];
    float acc[DIN];
#pragma unroll
    for (int d = 0; d < DIN; d++) acc[d] = 0.f;

    for (int e = start + sub; e < end; e += 8) {
        unsigned long long raw =
            __builtin_nontemporal_load((const unsigned long long*)(csr + e));
        int src    = (int)(unsigned)raw;
        float ewdd = __uint_as_float((unsigned)(raw >> 32));
        const uint4* hr = hin + (size_t)src * ROWW;
        if constexpr (DIN == 12) {
            uint4 ua = hr[0], ub = hr[1];
            float norm = ewdd * __uint_as_float(ub.z);
            h8 a = __builtin_bit_cast(h8, ua);
            h8 b = __builtin_bit_cast(h8, ub);
#pragma unroll
            for (int d = 0; d < 8; d++) acc[d] += norm * (float)a[d];
#pragma unroll
            for (int d = 0; d < 4; d++) acc[8 + d] += norm * (float)b[d];
        } else if constexpr (DIN == 6) {
            uint4 u = hr[0];
            float norm = ewdd * __uint_as_float(u.w);
            h8 a = __builtin_bit_cast(h8, u);
#pragma unroll
            for (int d = 0; d < 6; d++) acc[d] += norm * (float)a[d];
        } else {  // DIN == 3
            uint4 u = hr[0];
            float norm = ewdd * __uint_as_float(u.z);
            h8 a = __builtin_bit_cast(h8, u);
#pragma unroll
            for (int d = 0; d < 3; d++) acc[d] += norm * (float)a[d];
        }
    }

#pragma unroll
    for (int d = 0; d < DIN; d++) {
        acc[d] += __shfl_xor(acc[d], 1, 64);
        acc[d] += __shfl_xor(acc[d], 2, 64);
        acc[d] += __shfl_xor(acc[d], 4, 64);
    }

    if (sub == 0) {
        const uint4* hn = hin + (size_t)node * ROWW;
        float v[DIN];
        float dn;
        if constexpr (DIN == 12) {
            uint4 ua = hn[0], ub = hn[1];
            dn = __uint_as_float(ub.z);
            float s2 = dn * dn;
            h8 a = __builtin_bit_cast(h8, ua);
            h8 b = __builtin_bit_cast(h8, ub);
#pragma unroll
            for (int d = 0; d < 8; d++) v[d] = fmaxf(acc[d] + s2 * (float)a[d] + b_this[d], 0.f);
#pragma unroll
            for (int d = 0; d < 4; d++) v[8 + d] = fmaxf(acc[8 + d] + s2 * (float)b[d] + b_this[8 + d], 0.f);
        } else if constexpr (DIN == 6) {
            uint4 u = hn[0];
            dn = __uint_as_float(u.w);
            float s2 = dn * dn;
            h8 a = __builtin_bit_cast(h8, u);
#pragma unroll
            for (int d = 0; d < 6; d++) v[d] = fmaxf(acc[d] + s2 * (float)a[d] + b_this[d], 0.f);
        } else {
            uint4 u = hn[0];
            dn = __uint_as_float(u.z);
            float s2 = dn * dn;
            h8 a = __builtin_bit_cast(h8, u);
#pragma unroll
            for (int d = 0; d < 3; d++) v[d] = fmaxf(acc[d] + s2 * (float)a[d] + b_this[d], 0.f);
        }
        if constexpr (!LAST) {
            float o[DOUT];
#pragma unroll
            for (int oo = 0; oo < DOUT; oo++) {
                float z = 0.f;
#pragma unroll
                for (int d = 0; d < DIN; d++) z += v[d] * W_next[d * DOUT + oo];
                o[oo] = z;
            }
            h8 w;
#pragma unroll
            for (int oo = 0; oo < 8; oo++) w[oo] = (_Float16)0.f;
#pragma unroll
            for (int oo = 0; oo < DOUT; oo++) w[oo] = (_Float16)o[oo];
            uint4 uw = __builtin_bit_cast(uint4, w);
            if constexpr (DOUT == 6) uw.w = __float_as_uint(dn);
            else                     uw.z = __float_as_uint(dn);
            ((uint4*)hout_v)[node] = uw;
        } else {
            float z = b_next[0];
#pragma unroll
            for (int d = 0; d < DIN; d++) z += v[d] * W_next[d];
            ((float*)hout_v)[node] = 1.0f / (1.0f + expf(-z));
        }
    }
}

// ---------------------------------------------------------------------------
extern "C" void kernel_launch(void* const* d_in, const int* in_sizes, int n_in,
                              void* d_out, int out_size, void* d_ws, size_t ws_size,
                              hipStream_t stream) {
    const float* X  = (const float*)d_in[0];
    const int*   ei = (const int*)d_in[1];
    const float* ew = (const float*)d_in[2];
    const float* W1 = (const float*)d_in[3];
    const float* b1 = (const float*)d_in[4];
    const float* W2 = (const float*)d_in[5];
    const float* b2 = (const float*)d_in[6];
    const float* W3 = (const float*)d_in[7];
    const float* b3 = (const float*)d_in[8];
    const float* Wl = (const float*)d_in[9];
    const float* bl = (const float*)d_in[10];
    float* out = (float*)d_out;

    const int N = in_sizes[0] / 128;
    const int E = in_sizes[1] / 2;
    const int* row = ei;
    const int* col = ei + E;
    const int nfine   = (N + RANGE - 1) >> RSHIFT;
    const int ncoarse = (N + CRANGE - 1) >> CSHIFT;

    char* ws = (char*)d_ws;
    size_t off = 0;
    auto carve = [&](size_t bytes) -> void* {
        void* p = ws + off;
        off += (bytes + 255) & ~(size_t)255;
        return p;
    };
    int*   fcnt    = (int*)  carve((size_t)MAXBUCK * PAD * 4);
    int*   fcur    = (int*)  carve((size_t)MAXBUCK * PAD * 4);
    int*   ccur    = (int*)  carve((size_t)MAXC * PAD * 4);
    int*   cbase   = (int*)  carve((size_t)(MAXC + 1) * 4);
    int*   fbase   = (int*)  carve((size_t)(MAXBUCK + 1) * 4);
    int*   row_ptr = (int*)  carve((size_t)(N + 1) * 4);
    float* dis     = (float*)carve((size_t)N * 4);
    uint2* partA   = (uint2*)carve((size_t)E * 8);
    uint2* partB   = (uint2*)carve((size_t)E * 8);
    // csr reuses partA (dead after fine scatter); t1/t2/t3 reuse partB
    uint2* csr = partA;
    uint4* t1  = (uint4*)partB;                 // N rows x 2 uint4 (32 B)
    uint4* t2  = t1 + (size_t)N * 2;            // N rows x 1 uint4 (16 B)
    uint4* t3  = t2 + (size_t)N;                // N rows x 1 uint4 (16 B)
    (void)ws_size; (void)n_in; (void)out_size;

    const int bCnt = (E + CH_CNT - 1) / CH_CNT;
    const int bSc  = (E + CH_SC - 1) / CH_SC;       // 1563 scatter blocks
    const int bL   = ((size_t)N * 8 + 255) / 256;   // lin1: 8 lanes per node
    const int bA   = ((size_t)N * 8 + 255) / 256;   // agg: 8 lanes per node

    zero_pad_kernel<<<(nfine + 255) / 256, 256, 0, stream>>>(fcnt, nfine);
    count_kernel<<<bCnt, 256, 0, stream>>>(col, fcnt, nfine, E);
    scan_kernel<<<1, 1024, 0, stream>>>(fcnt, fbase, fcur, cbase, ccur, row_ptr,
                                        nfine, ncoarse, N, E);
    coarse_scatter_kernel<<<bSc, 256, 0, stream>>>(row, col, ew, ccur, partA, ncoarse, E);
    fine_scatter_kernel<<<bSc, 256, 0, stream>>>(partA, cbase, fcur, partB, nfine, ncoarse, E);
    bucket_csr_kernel<<<nfine, 256, 0, stream>>>(partB, fbase, row_ptr, dis, csr, N);
    lin1_kernel<<<bL, 256, 0, stream>>>(X, W1, dis, t1, N);
    agg_kernel<12, 2, 6, false><<<bA, 256, 0, stream>>>(row_ptr, csr, t1, b1, W2, nullptr, t2, N);
    agg_kernel< 6, 1, 3, false><<<bA, 256, 0, stream>>>(row_ptr, csr, t2, b2, W3, nullptr, t3, N);
    agg_kernel< 3, 1, 1, true ><<<bA, 256, 0, stream>>>(row_ptr, csr, t3, b3, Wl, bl, out, N);
}